// Round 4
// baseline (1817.562 us; speedup 1.0000x reference)
//
#include <hip/hip_runtime.h>
#include <stdint.h>

// SetAbstraction (PointNet++): B=4, N=8192, C=128, S=2048, K=32, R=0.1
// Numerics locked (R5 passed, absmax 0.0156):
//  - FPS: f32, d = ((dx*dx + dy*dy) + dz*dz) mul/add LTR (np.sum order)
//  - grouping: sq = (cc+pp) - 2*dot, dot = fma(cz,z, fma(cy,y, cx*x)) (BLAS)
//  - MLP: bf16 MFMA
// R12: kfps width halved -- 512 threads (8 waves), 16 pts/lane. Skip-path
// VALU issue, barrier arrival, and same-address atomicMax fan-in all scale
// with wave count and dominate post-R11 (VALUBusy 47% of active CU, rest
// stall). Update path doubles per wave but updating waves are the minority
// (per-lane exact skip, R11) and their count also halves. Combine skeleton
// (sp[far] read, 4-slot rotating LDS atomicMax) untouched per R9/R10 lessons.

typedef unsigned short u16;
typedef unsigned long long u64;
typedef __bf16 bf16x8 __attribute__((ext_vector_type(8)));
typedef float f32x4 __attribute__((ext_vector_type(4)));
typedef float f32x2 __attribute__((ext_vector_type(2)));

#define NB 4
#define NPTS 8192
#define CH 128
#define SPTS 2048
#define KN 32
#define CINP 160   // 131 padded to 160 (5 k-steps of 32)

__device__ __forceinline__ u16 f2b(float f) {  // f32 -> bf16 RNE
    unsigned x = __float_as_uint(f);
    unsigned r = (x + 0x7fffu + ((x >> 16) & 1u)) >> 16;
    return (u16)r;
}
__device__ __forceinline__ u64 umin64(u64 a, u64 b) { return a < b ? a : b; }

template <int CTRL>
__device__ __forceinline__ u64 dpp_max64(u64 k) {
    unsigned lo = (unsigned)k, hi = (unsigned)(k >> 32);
    unsigned mlo = (unsigned)__builtin_amdgcn_update_dpp((int)lo, (int)lo, CTRL, 0xF, 0xF, false);
    unsigned mhi = (unsigned)__builtin_amdgcn_update_dpp((int)hi, (int)hi, CTRL, 0xF, 0xF, false);
    u64 m = ((u64)mhi << 32) | mlo;
    return m > k ? m : k;
}
// uint-bits max (== float max for non-negative floats)
template <int CTRL>
__device__ __forceinline__ unsigned dpp_maxu(unsigned v) {
    unsigned mv = (unsigned)__builtin_amdgcn_update_dpp((int)v, (int)v, CTRL, 0xF, 0xF, false);
    return mv > v ? mv : v;
}

// ---------------- transpose fea (B,C,N) f32 -> feaT (B,N,C) bf16 ----------------
__global__ __launch_bounds__(256) void ktrans(const float* __restrict__ fea,
                                              u16* __restrict__ feaT) {
    __shared__ u16 T[128][130];
    int blk = blockIdx.x;  // 4 b x 64 n-tiles
    int b = blk >> 6, nt = blk & 63;
    int n0 = nt * 128;
    int t = threadIdx.x;
#pragma unroll 4
    for (int it = 0; it < 64; ++it) {
        int idx = it * 256 + t;
        int c = idx >> 7, nl = idx & 127;
        T[nl][c] = f2b(fea[((size_t)(b * CH + c)) * NPTS + n0 + nl]);
    }
    __syncthreads();
#pragma unroll 4
    for (int it = 0; it < 64; ++it) {
        int idx = it * 256 + t;
        int nl = idx >> 7, c = idx & 127;
        feaT[((size_t)(b * NPTS + n0 + nl)) * CH + c] = T[nl][c];
    }
}

// ---------------- pp = |p|^2 (np.sum LTR), W pad to bf16 ----------------
__global__ __launch_bounds__(256) void kmisc(const float* __restrict__ coor,
                                             const float* __restrict__ W,
                                             float* __restrict__ pp,
                                             u16* __restrict__ Wpad) {
    int gid = blockIdx.x * 256 + threadIdx.x;
    if (blockIdx.x < 128) {
        int n = gid & 8191, b = gid >> 13;
        const float* cb = coor + b * 3 * NPTS;
        float x = cb[n], y = cb[NPTS + n], z = cb[2 * NPTS + n];
        pp[gid] = __fadd_rn(__fadd_rn(__fmul_rn(x, x), __fmul_rn(y, y)),
                            __fmul_rn(z, z));
    } else {
        int i = gid - 128 * 256;
        if (i < 256 * CINP) {
            int d = i / CINP, k = i - d * CINP;
            Wpad[i] = (k < 131) ? f2b(W[d * 131 + k]) : (u16)0;
        }
    }
}

// ------- spatial counting sort into 256 bins: 16 xy-cells x 16 z-slices -------
__global__ __launch_bounds__(256) void ksort(const float* __restrict__ coor,
                                             float* __restrict__ sxg,
                                             float* __restrict__ syg,
                                             float* __restrict__ szg,
                                             int* __restrict__ sog) {
    __shared__ int hist[256], base[256];
    int b = blockIdx.x, tid = threadIdx.x;
    const float* cb = coor + b * 3 * NPTS;
    hist[tid] = 0;
    __syncthreads();
    int bins[32];
#pragma unroll 4
    for (int i = 0; i < 32; ++i) {
        int n = tid * 32 + i;
        float x = cb[n], y = cb[NPTS + n], z = cb[2 * NPTS + n];
        int bx = min(3, (int)(x * 4.0f));
        int by = min(3, (int)(y * 4.0f));
        int bz = min(15, (int)(z * 16.0f));
        int bin = ((by * 4 + bx) << 4) | bz;   // xy-major, z-minor
        bins[i] = bin;
        atomicAdd(&hist[bin], 1);
    }
    __syncthreads();
    if (tid == 0) {
        int acc = 0;
        for (int k2 = 0; k2 < 256; ++k2) { base[k2] = acc; acc += hist[k2]; hist[k2] = 0; }
    }
    __syncthreads();
#pragma unroll 4
    for (int i = 0; i < 32; ++i) {
        int n = tid * 32 + i;
        int bin = bins[i];
        int pos = base[bin] + atomicAdd(&hist[bin], 1);
        sxg[b * NPTS + pos] = cb[n];
        syg[b * NPTS + pos] = cb[NPTS + n];
        szg[b * NPTS + pos] = cb[2 * NPTS + n];
        sog[b * NPTS + pos] = n;
    }
}

// ---------------- FPS v8: 1 block (512 thr, 16 pts/lane) per batch ----------------
__global__ __launch_bounds__(512) void kfps(const float* __restrict__ sxg,
                                            const float* __restrict__ syg,
                                            const float* __restrict__ szg,
                                            const int* __restrict__ sog,
                                            int* __restrict__ fpsIdx,
                                            float* __restrict__ outCoor) {
    __shared__ float4 sp[NPTS];          // 128 KB
    __shared__ unsigned sWin[SPTS];      // 8 KB
    __shared__ u64 sAtom[4];
    __shared__ int slot0s;
    int tid = threadIdx.x;
    int b = blockIdx.x;
    int lane = tid & 63;
    const float* gx = sxg + b * NPTS;
    const float* gy = syg + b * NPTS;
    const float* gz = szg + b * NPTS;
    const int* go = sog + b * NPTS;
    f32x2 X2[8], Y2[8], Z2[8], D2[8];
    unsigned PK[16];
    int n0 = tid * 16;
    if (tid < 4) sAtom[tid] = 0;
    float lox, hix, loy, hiy, loz, hiz;  // per-lane bbox of this lane's 16 pts
#pragma unroll
    for (int j = 0; j < 16; ++j) {
        float x = gx[n0 + j], y = gy[n0 + j], z = gz[n0 + j];
        sp[n0 + j] = make_float4(x, y, z, 0.0f);
        X2[j >> 1][j & 1] = x; Y2[j >> 1][j & 1] = y; Z2[j >> 1][j & 1] = z;
        D2[j >> 1][j & 1] = 1e10f;
        int oi = go[n0 + j];
        PK[j] = ((unsigned)oi << 16) | (unsigned)(n0 + j);
        if (oi == 0) slot0s = n0 + j;
        if (j == 0) {
            lox = hix = x; loy = hiy = y; loz = hiz = z;
        } else {
            lox = fminf(lox, x); hix = fmaxf(hix, x);
            loy = fminf(loy, y); hiy = fmaxf(hiy, y);
            loz = fminf(loz, z); hiz = fmaxf(hiz, z);
        }
    }
    __syncthreads();
    int far = slot0s;
    if (tid == 0) sWin[0] = (unsigned)slot0s;  // origIdx 0 in high bits
    float lm = 3.4e38f;     // lane max D (exact); forces update on first iter
    u64 cachedKey = 1;      // any real key beats it
    for (int t = 1; t < SPTS; ++t) {
        float4 c = sp[far];  // uniform addr -> broadcast ds_read_b128
        float fx = c.x, fy = c.y, fz = c.z;
        // exact per-lane skip: min dist(c, lane bbox)^2 vs lane max D
        float ddx = fmaxf(0.0f, fmaxf(lox - fx, fx - hix));
        float ddy = fmaxf(0.0f, fmaxf(loy - fy, fy - hiy));
        float ddz = fmaxf(0.0f, fmaxf(loz - fz, fz - hiz));
        float dmin2 = ddx * ddx + ddy * ddy + ddz * ddz;
        if (__ballot(dmin2 * 0.9995f < lm) != 0ull) {  // any lane might change
            {
#pragma clang fp contract(off)
                f32x2 fx2 = {fx, fx}, fy2 = {fy, fy}, fz2 = {fz, fz};
#pragma unroll
                for (int i = 0; i < 8; ++i) {
                    f32x2 dx = X2[i] - fx2;
                    f32x2 dy = Y2[i] - fy2;
                    f32x2 dz = Z2[i] - fz2;
                    f32x2 s = (dx * dx + dy * dy) + dz * dz;  // per-elem RN, np order
                    D2[i] = __builtin_elementwise_min(D2[i], s);
                }
            }
            // thread argmax: packed value tree, then min-PK among ties
            f32x2 u0 = __builtin_elementwise_max(D2[0], D2[1]);
            f32x2 u1 = __builtin_elementwise_max(D2[2], D2[3]);
            f32x2 u2 = __builtin_elementwise_max(D2[4], D2[5]);
            f32x2 u3 = __builtin_elementwise_max(D2[6], D2[7]);
            f32x2 v0 = __builtin_elementwise_max(u0, u1);
            f32x2 v1 = __builtin_elementwise_max(u2, u3);
            f32x2 w0 = __builtin_elementwise_max(v0, v1);
            float m = fmaxf(w0[0], w0[1]);
            lm = m;  // lane max D, exact
            unsigned sel = 0xFFFFFFFFu;
#pragma unroll
            for (int j = 0; j < 16; ++j) {
                float dj = D2[j >> 1][j & 1];
                sel = (dj == m) ? (sel < PK[j] ? sel : PK[j]) : sel;
            }
            // wave value-max via DPP on float bits (all >= 0)
            unsigned mbits = __float_as_uint(m);
            unsigned r = mbits;
            r = dpp_maxu<0xB1>(r);    // quad_perm xor1
            r = dpp_maxu<0x4E>(r);    // quad_perm xor2
            r = dpp_maxu<0x141>(r);   // row_half_mirror
            r = dpp_maxu<0x140>(r);   // row_mirror
            r = dpp_maxu<0x142>(r);   // row_bcast:15
            r = dpp_maxu<0x143>(r);   // row_bcast:31
            unsigned wmaxb = (unsigned)__builtin_amdgcn_readlane((int)r, 63);
            u64 ball = __ballot(mbits == wmaxb);
            unsigned wpk;
            if (__popcll(ball) == 1) {  // unique winner lane (common)
                int l = __ffsll(ball) - 1;
                wpk = (unsigned)__builtin_amdgcn_readlane((int)sel, l);
            } else {                    // rare: cross-lane value tie
                u64 kk = (mbits == wmaxb) ? (((u64)wmaxb << 32) | (unsigned)~sel) : 0ull;
                kk = dpp_max64<0xB1>(kk);
                kk = dpp_max64<0x4E>(kk);
                kk = dpp_max64<0x141>(kk);
                kk = dpp_max64<0x140>(kk);
                kk = dpp_max64<0x142>(kk);
                kk = dpp_max64<0x143>(kk);
                unsigned lo = (unsigned)__builtin_amdgcn_readlane((int)(unsigned)kk, 63);
                wpk = ~lo;
            }
            cachedKey = ((u64)wmaxb << 32) | (unsigned)~wpk;
        }
        if (lane == 63) atomicMax(&sAtom[t & 3], cachedKey);
        if (tid == 0) sAtom[(t + 1) & 3] = 0;  // slot quiescent this window
        __syncthreads();
        u64 wk = sAtom[t & 3];  // broadcast ds_read_b64
        unsigned pk = ~(unsigned)wk;
        far = (int)(pk & 0xFFFFu);
        if (tid == 0) sWin[t] = pk;
    }
    __syncthreads();
    // deferred flush
    for (int i = tid; i < SPTS; i += 512) {
        unsigned pk = sWin[i];
        int slot = (int)(pk & 0xFFFFu);
        float4 c = sp[slot];
        fpsIdx[b * SPTS + i] = (int)(pk >> 16);
        float* oc = outCoor + b * 3 * SPTS + i;
        oc[0] = c.x; oc[SPTS] = c.y; oc[2 * SPTS] = c.z;
    }
}

// ---------------- grouping (exact f32, GEMM-style FMA dot): 1 wave/row ----------------
__global__ __launch_bounds__(256) void kgroup(const float* __restrict__ coor,
                                              const float* __restrict__ pp,
                                              const int* __restrict__ fpsIdx,
                                              int* __restrict__ gidxOut) {
    __shared__ u64 buf[4][256];
    __shared__ int cnt[4];
    int tid = threadIdx.x;
    int wv = tid >> 6, lane = tid & 63;
    if (tid < 4) cnt[tid] = 0;
    __syncthreads();
    int row = blockIdx.x * 4 + wv;
    int b = row >> 11, s = row & 2047;
    const float* cb = coor + b * 3 * NPTS;
    int n0 = fpsIdx[b * SPTS + s];
    float cx = cb[n0], cy = cb[NPTS + n0], cz = cb[2 * NPTS + n0];
    float cc = __fadd_rn(__fadd_rn(__fmul_rn(cx, cx), __fmul_rn(cy, cy)),
                         __fmul_rn(cz, cz));
    const float* ppb = pp + b * NPTS;
    u64 mk = ~0ull;
    for (int n = lane; n < NPTS; n += 64) {
        float x = cb[n], y = cb[NPTS + n], z = cb[2 * NPTS + n];
        float dot = __fmaf_rn(cz, z, __fmaf_rn(cy, y, __fmul_rn(cx, x)));
        float sq = __fsub_rn(__fadd_rn(cc, ppb[n]), __fmul_rn(2.0f, dot));
        unsigned ub = __float_as_uint(sq);
        ub ^= (ub >> 31) ? 0xFFFFFFFFu : 0x80000000u;
        u64 key = ((u64)ub << 32) | (unsigned)n;
        mk = umin64(mk, key);
        if (sq <= 0.01f) {
            int p = atomicAdd(&cnt[wv], 1);
            if (p < 256) buf[wv][p] = key;
        }
    }
#pragma unroll
    for (int off = 32; off > 0; off >>= 1) mk = umin64(mk, __shfl_xor(mk, off));
    int C = cnt[wv];
    if (C > 256) C = 256;
    int* go = gidxOut + row * KN;
    if (C <= 32) {
        if (lane < 32) {
            unsigned idx = (lane < C) ? (unsigned)buf[wv][lane] : (unsigned)mk;
            go[lane] = (int)idx;
        }
    } else {
        u64 e[4];
#pragma unroll
        for (int i = 0; i < 4; ++i) {
            int j2 = lane + (i << 6);
            e[i] = (j2 < C) ? buf[wv][j2] : ~0ull;
        }
        int cl = 0;
        unsigned sel = 0;
        for (int it = 0; it < 32; ++it) {
            u64 lb = ~0ull;
            int li = 0;
#pragma unroll
            for (int i = 0; i < 4; ++i) {
                bool f = (((cl >> i) & 1) == 0) && (e[i] < lb);
                lb = f ? e[i] : lb;
                li = f ? i : li;
            }
            u64 wmin = lb;
#pragma unroll
            for (int off = 32; off > 0; off >>= 1) wmin = umin64(wmin, __shfl_xor(wmin, off));
            u64 bal = __ballot(lb == wmin);
            int src = __ffsll((unsigned long long)bal) - 1;
            if (lane == src) cl |= (1 << li);
            if (lane == it) sel = (unsigned)wmin;
        }
        if (lane < 32) go[lane] = (int)sel;
    }
}

// ---------------- MLP + BN + ReLU + maxpool: 1 block per (b,s) row ----------------
__global__ __launch_bounds__(256) void kfeat(const float* __restrict__ coor,
                                             const u16* __restrict__ feaT,
                                             const u16* __restrict__ Wpad,
                                             const float* __restrict__ bias,
                                             const float* __restrict__ gamma,
                                             const float* __restrict__ beta,
                                             const float* __restrict__ bmean,
                                             const float* __restrict__ bvar,
                                             const int* __restrict__ fpsIdx,
                                             const int* __restrict__ gidx,
                                             float* __restrict__ outFea) {
    __shared__ u16 g[KN][168];
    int row = blockIdx.x;
    int b = row >> 11, s = row & 2047;
    int tid = threadIdx.x;
    {
        int k = tid >> 3, j = tid & 7;
        const float* cb = coor + b * 3 * NPTS;
        int nc = fpsIdx[b * SPTS + s];
        int nbr = gidx[row * KN + k];
        const uint4* f4 = (const uint4*)(feaT + (((size_t)b * NPTS + nbr) << 7));
        uint4* gr = (uint4*)&g[k][0];
        gr[j] = f4[j];
        gr[j + 8] = f4[j + 8];
        for (int c = 128 + j; c < CINP; c += 8) {
            u16 v = 0;
            if (c < 131) {
                int dim = c - 128;
                float pv = cb[dim * NPTS + nbr];
                float cv = cb[dim * NPTS + nc];
                v = f2b(__fdiv_rn(__fsub_rn(pv, cv), 0.1f));
            }
            g[k][c] = v;
        }
    }
    __syncthreads();
    int w = tid >> 6, lane = tid & 63;
    int mrow = lane & 15, q = lane >> 4;
    f32x4 acc[4][2] = {};
#pragma unroll
    for (int ks = 0; ks < 5; ++ks) {
        int kb = ks * 32 + q * 8;
        bf16x8 b0 = *(const bf16x8*)&g[mrow][kb];
        bf16x8 b1 = *(const bf16x8*)&g[mrow + 16][kb];
#pragma unroll
        for (int mt = 0; mt < 4; ++mt) {
            bf16x8 a = *(const bf16x8*)&Wpad[(size_t)(w * 64 + mt * 16 + mrow) * CINP + kb];
            acc[mt][0] = __builtin_amdgcn_mfma_f32_16x16x32_bf16(a, b0, acc[mt][0], 0, 0, 0);
            acc[mt][1] = __builtin_amdgcn_mfma_f32_16x16x32_bf16(a, b1, acc[mt][1], 0, 0, 0);
        }
    }
#pragma unroll
    for (int mt = 0; mt < 4; ++mt) {
#pragma unroll
        for (int r = 0; r < 4; ++r) {
            int m = w * 64 + mt * 16 + q * 4 + r;
            float ga = gamma[m], be = beta[m];
            float mu = bmean[m], va = bvar[m], bi = bias[m];
            float rs = 1.0f / sqrtf(va + 1e-5f);
            float h0 = acc[mt][0][r] + bi;
            h0 = fmaxf(ga * (h0 - mu) * rs + be, 0.0f);
            float h1 = acc[mt][1][r] + bi;
            h1 = fmaxf(ga * (h1 - mu) * rs + be, 0.0f);
            float v = fmaxf(h0, h1);
#pragma unroll
            for (int off = 1; off < 16; off <<= 1) v = fmaxf(v, __shfl_xor(v, off));
            if (mrow == 0) outFea[((size_t)(b * 256 + m)) * SPTS + s] = v;
        }
    }
}

extern "C" void kernel_launch(void* const* d_in, const int* in_sizes, int n_in,
                              void* d_out, int out_size, void* d_ws, size_t ws_size,
                              hipStream_t stream) {
    const float* coor = (const float*)d_in[0];
    const float* fea = (const float*)d_in[1];
    const float* W = (const float*)d_in[2];
    const float* bias = (const float*)d_in[3];
    const float* gamma = (const float*)d_in[4];
    const float* beta = (const float*)d_in[5];
    const float* bmean = (const float*)d_in[6];
    const float* bvar = (const float*)d_in[7];
    char* ws = (char*)d_ws;
    int* fpsIdx = (int*)ws;                              // 32 KB
    int* gidx = (int*)(ws + 32768);                      // 1 MB
    float* pp = (float*)(ws + 32768 + 1048576);          // 128 KB
    u16* feaT = (u16*)(ws + 1212416);                    // 8 MB bf16
    u16* Wpad = (u16*)(ws + 9601024);                    // 80 KB bf16
    float* sxg = (float*)(ws + 9682944);                 // 128 KB
    float* syg = (float*)(ws + 9814016);                 // 128 KB
    float* szg = (float*)(ws + 9945088);                 // 128 KB
    int* sog = (int*)(ws + 10076160);                    // 128 KB
    float* outC = (float*)d_out;                         // (B,3,S) f32
    float* outF = outC + NB * 3 * SPTS;                  // (B,2C,S) f32

    ktrans<<<256, 256, 0, stream>>>(fea, feaT);
    kmisc<<<288, 256, 0, stream>>>(coor, W, pp, Wpad);
    ksort<<<NB, 256, 0, stream>>>(coor, sxg, syg, szg, sog);
    kfps<<<NB, 512, 0, stream>>>(sxg, syg, szg, sog, fpsIdx, outC);
    kgroup<<<2048, 256, 0, stream>>>(coor, pp, fpsIdx, gidx);
    kfeat<<<8192, 256, 0, stream>>>(coor, feaT, Wpad, bias, gamma, beta, bmean, bvar,
                                    fpsIdx, gidx, outF);
}

// Round 5
// 1764.124 us; speedup vs baseline: 1.0303x; 1.0303x over previous
//
#include <hip/hip_runtime.h>
#include <stdint.h>

// SetAbstraction (PointNet++): B=4, N=8192, C=128, S=2048, K=32, R=0.1
// Numerics locked (R5 passed, absmax 0.0156):
//  - FPS: f32, d = ((dx*dx + dy*dy) + dz*dz) mul/add LTR (np.sum order)
//  - grouping: sq = (cc+pp) - 2*dot, dot = fma(cz,z, fma(cy,y, cx*x)) (BLAS)
//  - MLP: bf16 MFMA
// R13: R11 skeleton (best measured: kfps 1387us) restored verbatim -- R12's
// 8-wave variant regressed (updating wave's doubled work is always on the
// barrier critical path; >=1 wave updates every iter since the new centroid's
// own wave always fails its skip test). New on top of R11:
//  - candidate-unchanged fast path (exact): winner lane keeps a bit-exact
//    scalar mirror of its candidate's D; if unchanged, cached (value,minPK)
//    key is provably still the exact wave argmax -> skip sel-scan+DPP+tie
//    (~36 instrs on the critical wave). Packed tree still refreshes lm.
//  - bbox test in center/half-extent form (abs input modifier), 3 instr/axis.
//  - ktrans+kmisc+ksort fused into one kprep launch (independent work).

typedef unsigned short u16;
typedef unsigned long long u64;
typedef __bf16 bf16x8 __attribute__((ext_vector_type(8)));
typedef float f32x4 __attribute__((ext_vector_type(4)));
typedef float f32x2 __attribute__((ext_vector_type(2)));

#define NB 4
#define NPTS 8192
#define CH 128
#define SPTS 2048
#define KN 32
#define CINP 160   // 131 padded to 160 (5 k-steps of 32)

__device__ __forceinline__ u16 f2b(float f) {  // f32 -> bf16 RNE
    unsigned x = __float_as_uint(f);
    unsigned r = (x + 0x7fffu + ((x >> 16) & 1u)) >> 16;
    return (u16)r;
}
__device__ __forceinline__ u64 umin64(u64 a, u64 b) { return a < b ? a : b; }

template <int CTRL>
__device__ __forceinline__ u64 dpp_max64(u64 k) {
    unsigned lo = (unsigned)k, hi = (unsigned)(k >> 32);
    unsigned mlo = (unsigned)__builtin_amdgcn_update_dpp((int)lo, (int)lo, CTRL, 0xF, 0xF, false);
    unsigned mhi = (unsigned)__builtin_amdgcn_update_dpp((int)hi, (int)hi, CTRL, 0xF, 0xF, false);
    u64 m = ((u64)mhi << 32) | mlo;
    return m > k ? m : k;
}
// uint-bits max (== float max for non-negative floats)
template <int CTRL>
__device__ __forceinline__ unsigned dpp_maxu(unsigned v) {
    unsigned mv = (unsigned)__builtin_amdgcn_update_dpp((int)v, (int)v, CTRL, 0xF, 0xF, false);
    return mv > v ? mv : v;
}

// ---- fused prep: ktrans (blocks 0-255) | kmisc (256-543) | ksort (544-547) ----
__global__ __launch_bounds__(256) void kprep(const float* __restrict__ fea,
                                             const float* __restrict__ coor,
                                             const float* __restrict__ W,
                                             u16* __restrict__ feaT,
                                             float* __restrict__ pp,
                                             u16* __restrict__ Wpad,
                                             float* __restrict__ sxg,
                                             float* __restrict__ syg,
                                             float* __restrict__ szg,
                                             int* __restrict__ sog) {
    __shared__ __align__(16) char raw[128 * 130 * 2];  // 33280 B, reused per role
    int bid = blockIdx.x;
    int t = threadIdx.x;
    if (bid < 256) {
        // ---- transpose fea (B,C,N) f32 -> feaT (B,N,C) bf16 ----
        u16(*T)[130] = (u16(*)[130])raw;
        int b = bid >> 6, nt = bid & 63;
        int n0 = nt * 128;
#pragma unroll 4
        for (int it = 0; it < 64; ++it) {
            int idx = it * 256 + t;
            int c = idx >> 7, nl = idx & 127;
            T[nl][c] = f2b(fea[((size_t)(b * CH + c)) * NPTS + n0 + nl]);
        }
        __syncthreads();
#pragma unroll 4
        for (int it = 0; it < 64; ++it) {
            int idx = it * 256 + t;
            int nl = idx >> 7, c = idx & 127;
            feaT[((size_t)(b * NPTS + n0 + nl)) * CH + c] = T[nl][c];
        }
    } else if (bid < 544) {
        // ---- pp = |p|^2 (np.sum LTR), W pad to bf16 ----
        int gid = (bid - 256) * 256 + t;
        if (bid < 384) {
            int n = gid & 8191, b = gid >> 13;
            const float* cb = coor + b * 3 * NPTS;
            float x = cb[n], y = cb[NPTS + n], z = cb[2 * NPTS + n];
            pp[gid] = __fadd_rn(__fadd_rn(__fmul_rn(x, x), __fmul_rn(y, y)),
                                __fmul_rn(z, z));
        } else {
            int i = gid - 128 * 256;
            if (i < 256 * CINP) {
                int d = i / CINP, k = i - d * CINP;
                Wpad[i] = (k < 131) ? f2b(W[d * 131 + k]) : (u16)0;
            }
        }
    } else {
        // ---- spatial counting sort into 256 bins: 16 xy-cells x 16 z-slices ----
        int* hist = (int*)raw;
        int* base = hist + 256;
        int b = bid - 544;
        const float* cb = coor + b * 3 * NPTS;
        hist[t] = 0;
        __syncthreads();
        int bins[32];
#pragma unroll 4
        for (int i = 0; i < 32; ++i) {
            int n = t * 32 + i;
            float x = cb[n], y = cb[NPTS + n], z = cb[2 * NPTS + n];
            int bx = min(3, (int)(x * 4.0f));
            int by = min(3, (int)(y * 4.0f));
            int bz = min(15, (int)(z * 16.0f));
            int bin = ((by * 4 + bx) << 4) | bz;   // xy-major, z-minor
            bins[i] = bin;
            atomicAdd(&hist[bin], 1);
        }
        __syncthreads();
        if (t == 0) {
            int acc = 0;
            for (int k2 = 0; k2 < 256; ++k2) { base[k2] = acc; acc += hist[k2]; hist[k2] = 0; }
        }
        __syncthreads();
#pragma unroll 4
        for (int i = 0; i < 32; ++i) {
            int n = t * 32 + i;
            int bin = bins[i];
            int pos = base[bin] + atomicAdd(&hist[bin], 1);
            sxg[b * NPTS + pos] = cb[n];
            syg[b * NPTS + pos] = cb[NPTS + n];
            szg[b * NPTS + pos] = cb[2 * NPTS + n];
            sog[b * NPTS + pos] = n;
        }
    }
}

// ---------------- FPS v9: 1 block (1024 thr, 8 pts/lane) per batch ----------------
__global__ __launch_bounds__(1024) void kfps(const float* __restrict__ sxg,
                                             const float* __restrict__ syg,
                                             const float* __restrict__ szg,
                                             const int* __restrict__ sog,
                                             int* __restrict__ fpsIdx,
                                             float* __restrict__ outCoor) {
    __shared__ float4 sp[NPTS];          // 128 KB
    __shared__ unsigned sWin[SPTS];      // 8 KB
    __shared__ u64 sAtom[4];
    __shared__ int slot0s;
    int tid = threadIdx.x;
    int b = blockIdx.x;
    int lane = tid & 63;
    const float* gx = sxg + b * NPTS;
    const float* gy = syg + b * NPTS;
    const float* gz = szg + b * NPTS;
    const int* go = sog + b * NPTS;
    f32x2 X2[4], Y2[4], Z2[4], D2[4];
    unsigned PK[8];
    int n0 = tid * 8;
    if (tid < 4) sAtom[tid] = 0;
    float lox, hix, loy, hiy, loz, hiz;  // per-lane bbox of this lane's 8 pts
#pragma unroll
    for (int j = 0; j < 8; ++j) {
        float x = gx[n0 + j], y = gy[n0 + j], z = gz[n0 + j];
        sp[n0 + j] = make_float4(x, y, z, 0.0f);
        X2[j >> 1][j & 1] = x; Y2[j >> 1][j & 1] = y; Z2[j >> 1][j & 1] = z;
        D2[j >> 1][j & 1] = 1e10f;
        int oi = go[n0 + j];
        PK[j] = ((unsigned)oi << 16) | (unsigned)(n0 + j);
        if (oi == 0) slot0s = n0 + j;
        if (j == 0) {
            lox = hix = x; loy = hiy = y; loz = hiz = z;
        } else {
            lox = fminf(lox, x); hix = fmaxf(hix, x);
            loy = fminf(loy, y); hiy = fmaxf(hiy, y);
            loz = fminf(loz, z); hiz = fmaxf(hiz, z);
        }
    }
    // center/half-extent form: dmin_axis = max(0, |f - c| - e)  (abs = input mod)
    float bcx = (lox + hix) * 0.5f, bex = (hix - lox) * 0.5f;
    float bcy = (loy + hiy) * 0.5f, bey = (hiy - loy) * 0.5f;
    float bcz = (loz + hiz) * 0.5f, bez = (hiz - loz) * 0.5f;
    __syncthreads();
    int far = slot0s;
    if (tid == 0) sWin[0] = (unsigned)slot0s;  // origIdx 0 in high bits
    float lm = 3.4e38f;     // lane max D (exact upper bound); forces first update
    float wMaxF = 3.4e38f;  // cached wave max (from last reduce)
    u64 cachedKey = 1;      // any real key beats it
    bool win = false;       // am I my wave's cached-winner lane?
    float bX = 0.f, bY = 0.f, bZ = 0.f;  // winner lane: candidate coords
    float cvD = 3.4e38f;                 // winner lane: exact mirror of candidate D
    for (int t = 1; t < SPTS; ++t) {
        float4 c = sp[far];  // uniform addr -> broadcast ds_read_b128
        float fx = c.x, fy = c.y, fz = c.z;
        // exact per-lane skip: min dist(c, lane bbox)^2 vs lane max D
        float ddx = fmaxf(0.0f, fabsf(fx - bcx) - bex);
        float ddy = fmaxf(0.0f, fabsf(fy - bcy) - bey);
        float ddz = fmaxf(0.0f, fabsf(fz - bcz) - bez);
        float dmin2 = ddx * ddx + ddy * ddy + ddz * ddz;
        if (__ballot(dmin2 * 0.9995f < lm) != 0ull) {  // any lane might change
            float sc;
            {
#pragma clang fp contract(off)
                f32x2 fx2 = {fx, fx}, fy2 = {fy, fy}, fz2 = {fz, fz};
#pragma unroll
                for (int i = 0; i < 4; ++i) {
                    f32x2 dx = X2[i] - fx2;
                    f32x2 dy = Y2[i] - fy2;
                    f32x2 dz = Z2[i] - fz2;
                    f32x2 s = (dx * dx + dy * dy) + dz * dz;  // per-elem RN, np order
                    D2[i] = __builtin_elementwise_min(D2[i], s);
                }
                // bit-exact scalar mirror of the candidate point's distance
                float cdx = bX - fx, cdy = bY - fy, cdz = bZ - fz;
                sc = (cdx * cdx + cdy * cdy) + cdz * cdz;
            }
            cvD = fminf(cvD, sc);
            // refresh lane max (exact) -- cheap packed tree
            f32x2 t01 = __builtin_elementwise_max(D2[0], D2[1]);
            f32x2 t23 = __builtin_elementwise_max(D2[2], D2[3]);
            f32x2 t03 = __builtin_elementwise_max(t01, t23);
            float m = fmaxf(t03[0], t03[1]);
            lm = m;
            // Exact fast path: D only decreases => nothing can rise to the old
            // wave max and the tie-set at it only shrinks. If the cached
            // candidate's own D is unchanged, cached (value, minPK) is still
            // the exact wave argmax -- skip sel-scan + DPP + tie logic.
            if (__ballot(win && (cvD == wMaxF)) == 0ull) {
                unsigned sel = 0xFFFFFFFFu;
#pragma unroll
                for (int j = 0; j < 8; ++j) {
                    float dj = D2[j >> 1][j & 1];
                    sel = (dj == m) ? (sel < PK[j] ? sel : PK[j]) : sel;
                }
                // wave value-max via DPP on float bits (all >= 0)
                unsigned mbits = __float_as_uint(m);
                unsigned r = mbits;
                r = dpp_maxu<0xB1>(r);    // quad_perm xor1
                r = dpp_maxu<0x4E>(r);    // quad_perm xor2
                r = dpp_maxu<0x141>(r);   // row_half_mirror
                r = dpp_maxu<0x140>(r);   // row_mirror
                r = dpp_maxu<0x142>(r);   // row_bcast:15
                r = dpp_maxu<0x143>(r);   // row_bcast:31
                unsigned wmaxb = (unsigned)__builtin_amdgcn_readlane((int)r, 63);
                u64 ball = __ballot(mbits == wmaxb);
                unsigned wpk;
                bool iw;
                if (__popcll(ball) == 1) {  // unique winner lane (common)
                    int l = __ffsll(ball) - 1;
                    wpk = (unsigned)__builtin_amdgcn_readlane((int)sel, l);
                    iw = (mbits == wmaxb);
                } else {                    // rare: cross-lane value tie
                    u64 kk = (mbits == wmaxb) ? (((u64)wmaxb << 32) | (unsigned)~sel) : 0ull;
                    kk = dpp_max64<0xB1>(kk);
                    kk = dpp_max64<0x4E>(kk);
                    kk = dpp_max64<0x141>(kk);
                    kk = dpp_max64<0x140>(kk);
                    kk = dpp_max64<0x142>(kk);
                    kk = dpp_max64<0x143>(kk);
                    unsigned lo = (unsigned)__builtin_amdgcn_readlane((int)(unsigned)kk, 63);
                    wpk = ~lo;
                    iw = (mbits == wmaxb) && ((unsigned)~sel == lo);
                }
                win = iw;
                if (iw) {  // exactly one lane per wave: capture candidate state
                    cvD = m;
#pragma unroll
                    for (int j = 0; j < 8; ++j) {
                        if (PK[j] == sel) {
                            bX = X2[j >> 1][j & 1];
                            bY = Y2[j >> 1][j & 1];
                            bZ = Z2[j >> 1][j & 1];
                        }
                    }
                }
                cachedKey = ((u64)wmaxb << 32) | (unsigned)~wpk;
                wMaxF = __uint_as_float(wmaxb);
            }
        }
        if (lane == 63) atomicMax(&sAtom[t & 3], cachedKey);
        if (tid == 0) sAtom[(t + 1) & 3] = 0;  // slot quiescent this window
        __syncthreads();
        u64 wk = sAtom[t & 3];  // broadcast ds_read_b64
        unsigned pk = ~(unsigned)wk;
        far = (int)(pk & 0xFFFFu);
        if (tid == 0) sWin[t] = pk;
    }
    __syncthreads();
    // deferred flush
    for (int i = tid; i < SPTS; i += 1024) {
        unsigned pk = sWin[i];
        int slot = (int)(pk & 0xFFFFu);
        float4 c = sp[slot];
        fpsIdx[b * SPTS + i] = (int)(pk >> 16);
        float* oc = outCoor + b * 3 * SPTS + i;
        oc[0] = c.x; oc[SPTS] = c.y; oc[2 * SPTS] = c.z;
    }
}

// ---------------- grouping (exact f32, GEMM-style FMA dot): 1 wave/row ----------------
__global__ __launch_bounds__(256) void kgroup(const float* __restrict__ coor,
                                              const float* __restrict__ pp,
                                              const int* __restrict__ fpsIdx,
                                              int* __restrict__ gidxOut) {
    __shared__ u64 buf[4][256];
    __shared__ int cnt[4];
    int tid = threadIdx.x;
    int wv = tid >> 6, lane = tid & 63;
    if (tid < 4) cnt[tid] = 0;
    __syncthreads();
    int row = blockIdx.x * 4 + wv;
    int b = row >> 11, s = row & 2047;
    const float* cb = coor + b * 3 * NPTS;
    int n0 = fpsIdx[b * SPTS + s];
    float cx = cb[n0], cy = cb[NPTS + n0], cz = cb[2 * NPTS + n0];
    float cc = __fadd_rn(__fadd_rn(__fmul_rn(cx, cx), __fmul_rn(cy, cy)),
                         __fmul_rn(cz, cz));
    const float* ppb = pp + b * NPTS;
    u64 mk = ~0ull;
    for (int n = lane; n < NPTS; n += 64) {
        float x = cb[n], y = cb[NPTS + n], z = cb[2 * NPTS + n];
        float dot = __fmaf_rn(cz, z, __fmaf_rn(cy, y, __fmul_rn(cx, x)));
        float sq = __fsub_rn(__fadd_rn(cc, ppb[n]), __fmul_rn(2.0f, dot));
        unsigned ub = __float_as_uint(sq);
        ub ^= (ub >> 31) ? 0xFFFFFFFFu : 0x80000000u;
        u64 key = ((u64)ub << 32) | (unsigned)n;
        mk = umin64(mk, key);
        if (sq <= 0.01f) {
            int p = atomicAdd(&cnt[wv], 1);
            if (p < 256) buf[wv][p] = key;
        }
    }
#pragma unroll
    for (int off = 32; off > 0; off >>= 1) mk = umin64(mk, __shfl_xor(mk, off));
    int C = cnt[wv];
    if (C > 256) C = 256;
    int* go = gidxOut + row * KN;
    if (C <= 32) {
        if (lane < 32) {
            unsigned idx = (lane < C) ? (unsigned)buf[wv][lane] : (unsigned)mk;
            go[lane] = (int)idx;
        }
    } else {
        u64 e[4];
#pragma unroll
        for (int i = 0; i < 4; ++i) {
            int j2 = lane + (i << 6);
            e[i] = (j2 < C) ? buf[wv][j2] : ~0ull;
        }
        int cl = 0;
        unsigned sel = 0;
        for (int it = 0; it < 32; ++it) {
            u64 lb = ~0ull;
            int li = 0;
#pragma unroll
            for (int i = 0; i < 4; ++i) {
                bool f = (((cl >> i) & 1) == 0) && (e[i] < lb);
                lb = f ? e[i] : lb;
                li = f ? i : li;
            }
            u64 wmin = lb;
#pragma unroll
            for (int off = 32; off > 0; off >>= 1) wmin = umin64(wmin, __shfl_xor(wmin, off));
            u64 bal = __ballot(lb == wmin);
            int src = __ffsll((unsigned long long)bal) - 1;
            if (lane == src) cl |= (1 << li);
            if (lane == it) sel = (unsigned)wmin;
        }
        if (lane < 32) go[lane] = (int)sel;
    }
}

// ---------------- MLP + BN + ReLU + maxpool: 1 block per (b,s) row ----------------
__global__ __launch_bounds__(256) void kfeat(const float* __restrict__ coor,
                                             const u16* __restrict__ feaT,
                                             const u16* __restrict__ Wpad,
                                             const float* __restrict__ bias,
                                             const float* __restrict__ gamma,
                                             const float* __restrict__ beta,
                                             const float* __restrict__ bmean,
                                             const float* __restrict__ bvar,
                                             const int* __restrict__ fpsIdx,
                                             const int* __restrict__ gidx,
                                             float* __restrict__ outFea) {
    __shared__ u16 g[KN][168];
    int row = blockIdx.x;
    int b = row >> 11, s = row & 2047;
    int tid = threadIdx.x;
    {
        int k = tid >> 3, j = tid & 7;
        const float* cb = coor + b * 3 * NPTS;
        int nc = fpsIdx[b * SPTS + s];
        int nbr = gidx[row * KN + k];
        const uint4* f4 = (const uint4*)(feaT + (((size_t)b * NPTS + nbr) << 7));
        uint4* gr = (uint4*)&g[k][0];
        gr[j] = f4[j];
        gr[j + 8] = f4[j + 8];
        for (int c = 128 + j; c < CINP; c += 8) {
            u16 v = 0;
            if (c < 131) {
                int dim = c - 128;
                float pv = cb[dim * NPTS + nbr];
                float cv = cb[dim * NPTS + nc];
                v = f2b(__fdiv_rn(__fsub_rn(pv, cv), 0.1f));
            }
            g[k][c] = v;
        }
    }
    __syncthreads();
    int w = tid >> 6, lane = tid & 63;
    int mrow = lane & 15, q = lane >> 4;
    f32x4 acc[4][2] = {};
#pragma unroll
    for (int ks = 0; ks < 5; ++ks) {
        int kb = ks * 32 + q * 8;
        bf16x8 b0 = *(const bf16x8*)&g[mrow][kb];
        bf16x8 b1 = *(const bf16x8*)&g[mrow + 16][kb];
#pragma unroll
        for (int mt = 0; mt < 4; ++mt) {
            bf16x8 a = *(const bf16x8*)&Wpad[(size_t)(w * 64 + mt * 16 + mrow) * CINP + kb];
            acc[mt][0] = __builtin_amdgcn_mfma_f32_16x16x32_bf16(a, b0, acc[mt][0], 0, 0, 0);
            acc[mt][1] = __builtin_amdgcn_mfma_f32_16x16x32_bf16(a, b1, acc[mt][1], 0, 0, 0);
        }
    }
#pragma unroll
    for (int mt = 0; mt < 4; ++mt) {
#pragma unroll
        for (int r = 0; r < 4; ++r) {
            int m = w * 64 + mt * 16 + q * 4 + r;
            float ga = gamma[m], be = beta[m];
            float mu = bmean[m], va = bvar[m], bi = bias[m];
            float rs = 1.0f / sqrtf(va + 1e-5f);
            float h0 = acc[mt][0][r] + bi;
            h0 = fmaxf(ga * (h0 - mu) * rs + be, 0.0f);
            float h1 = acc[mt][1][r] + bi;
            h1 = fmaxf(ga * (h1 - mu) * rs + be, 0.0f);
            float v = fmaxf(h0, h1);
#pragma unroll
            for (int off = 1; off < 16; off <<= 1) v = fmaxf(v, __shfl_xor(v, off));
            if (mrow == 0) outFea[((size_t)(b * 256 + m)) * SPTS + s] = v;
        }
    }
}

extern "C" void kernel_launch(void* const* d_in, const int* in_sizes, int n_in,
                              void* d_out, int out_size, void* d_ws, size_t ws_size,
                              hipStream_t stream) {
    const float* coor = (const float*)d_in[0];
    const float* fea = (const float*)d_in[1];
    const float* W = (const float*)d_in[2];
    const float* bias = (const float*)d_in[3];
    const float* gamma = (const float*)d_in[4];
    const float* beta = (const float*)d_in[5];
    const float* bmean = (const float*)d_in[6];
    const float* bvar = (const float*)d_in[7];
    char* ws = (char*)d_ws;
    int* fpsIdx = (int*)ws;                              // 32 KB
    int* gidx = (int*)(ws + 32768);                      // 1 MB
    float* pp = (float*)(ws + 32768 + 1048576);          // 128 KB
    u16* feaT = (u16*)(ws + 1212416);                    // 8 MB bf16
    u16* Wpad = (u16*)(ws + 9601024);                    // 80 KB bf16
    float* sxg = (float*)(ws + 9682944);                 // 128 KB
    float* syg = (float*)(ws + 9814016);                 // 128 KB
    float* szg = (float*)(ws + 9945088);                 // 128 KB
    int* sog = (int*)(ws + 10076160);                    // 128 KB
    float* outC = (float*)d_out;                         // (B,3,S) f32
    float* outF = outC + NB * 3 * SPTS;                  // (B,2C,S) f32

    kprep<<<548, 256, 0, stream>>>(fea, coor, W, feaT, pp, Wpad, sxg, syg, szg, sog);
    kfps<<<NB, 1024, 0, stream>>>(sxg, syg, szg, sog, fpsIdx, outC);
    kgroup<<<2048, 256, 0, stream>>>(coor, pp, fpsIdx, gidx);
    kfeat<<<8192, 256, 0, stream>>>(coor, feaT, Wpad, bias, gamma, beta, bmean, bvar,
                                    fpsIdx, gidx, outF);
}

// Round 6
// 1663.695 us; speedup vs baseline: 1.0925x; 1.0604x over previous
//
#include <hip/hip_runtime.h>
#include <stdint.h>

// SetAbstraction (PointNet++): B=4, N=8192, C=128, S=2048, K=32, R=0.1
// Numerics locked (R5 passed, absmax 0.0156):
//  - FPS: f32, d = ((dx*dx + dy*dy) + dz*dz) mul/add LTR (np.sum order)
//  - grouping: sq = (cc+pp) - 2*dot, dot = fma(cz,z, fma(cy,y, cx*x)) (BLAS)
//  - MLP: bf16 MFMA
// R14: kfps FPS loop reverted to R11 VERBATIM (best measured: 1387us).
// R10/R13 both showed the candidate-mirror fast path regresses (+8%) despite
// lower VALUBusy: the slowest wave's branch-free latency chain is the binding
// constraint, not issue count. New lever is purely structural: during kfps
// only 4/256 CUs are active, so ktrans+kmisc (independent of FPS; only ksort
// is a dependency) are folded into the kfps dispatch as extra blocks that run
// concurrently on idle CUs. Grid 140: blocks 0-3 FPS, 4-67 transpose (4 tiles
// each), 68-99 pp, 100-139 Wpad. FPS code/numerics untouched.

typedef unsigned short u16;
typedef unsigned long long u64;
typedef __bf16 bf16x8 __attribute__((ext_vector_type(8)));
typedef float f32x4 __attribute__((ext_vector_type(4)));
typedef float f32x2 __attribute__((ext_vector_type(2)));

#define NB 4
#define NPTS 8192
#define CH 128
#define SPTS 2048
#define KN 32
#define CINP 160   // 131 padded to 160 (5 k-steps of 32)

__device__ __forceinline__ u16 f2b(float f) {  // f32 -> bf16 RNE
    unsigned x = __float_as_uint(f);
    unsigned r = (x + 0x7fffu + ((x >> 16) & 1u)) >> 16;
    return (u16)r;
}
__device__ __forceinline__ u64 umin64(u64 a, u64 b) { return a < b ? a : b; }

template <int CTRL>
__device__ __forceinline__ u64 dpp_max64(u64 k) {
    unsigned lo = (unsigned)k, hi = (unsigned)(k >> 32);
    unsigned mlo = (unsigned)__builtin_amdgcn_update_dpp((int)lo, (int)lo, CTRL, 0xF, 0xF, false);
    unsigned mhi = (unsigned)__builtin_amdgcn_update_dpp((int)hi, (int)hi, CTRL, 0xF, 0xF, false);
    u64 m = ((u64)mhi << 32) | mlo;
    return m > k ? m : k;
}
// uint-bits max (== float max for non-negative floats)
template <int CTRL>
__device__ __forceinline__ unsigned dpp_maxu(unsigned v) {
    unsigned mv = (unsigned)__builtin_amdgcn_update_dpp((int)v, (int)v, CTRL, 0xF, 0xF, false);
    return mv > v ? mv : v;
}

// ------- spatial counting sort into 256 bins: 16 xy-cells x 16 z-slices -------
__global__ __launch_bounds__(256) void ksort(const float* __restrict__ coor,
                                             float* __restrict__ sxg,
                                             float* __restrict__ syg,
                                             float* __restrict__ szg,
                                             int* __restrict__ sog) {
    __shared__ int hist[256], base[256];
    int b = blockIdx.x, tid = threadIdx.x;
    const float* cb = coor + b * 3 * NPTS;
    hist[tid] = 0;
    __syncthreads();
    int bins[32];
#pragma unroll 4
    for (int i = 0; i < 32; ++i) {
        int n = tid * 32 + i;
        float x = cb[n], y = cb[NPTS + n], z = cb[2 * NPTS + n];
        int bx = min(3, (int)(x * 4.0f));
        int by = min(3, (int)(y * 4.0f));
        int bz = min(15, (int)(z * 16.0f));
        int bin = ((by * 4 + bx) << 4) | bz;   // xy-major, z-minor
        bins[i] = bin;
        atomicAdd(&hist[bin], 1);
    }
    __syncthreads();
    if (tid == 0) {
        int acc = 0;
        for (int k2 = 0; k2 < 256; ++k2) { base[k2] = acc; acc += hist[k2]; hist[k2] = 0; }
    }
    __syncthreads();
#pragma unroll 4
    for (int i = 0; i < 32; ++i) {
        int n = tid * 32 + i;
        int bin = bins[i];
        int pos = base[bin] + atomicAdd(&hist[bin], 1);
        sxg[b * NPTS + pos] = cb[n];
        syg[b * NPTS + pos] = cb[NPTS + n];
        szg[b * NPTS + pos] = cb[2 * NPTS + n];
        sog[b * NPTS + pos] = n;
    }
}

// ---- FPS mega-dispatch: blocks 0-3 FPS (R11 verbatim); 4-67 ktrans;
// ---- 68-99 pp; 100-139 Wpad. Aux blocks run on idle CUs concurrently.
__global__ __launch_bounds__(1024) void kfps(const float* __restrict__ sxg,
                                             const float* __restrict__ syg,
                                             const float* __restrict__ szg,
                                             const int* __restrict__ sog,
                                             int* __restrict__ fpsIdx,
                                             float* __restrict__ outCoor,
                                             const float* __restrict__ fea,
                                             const float* __restrict__ coor,
                                             const float* __restrict__ W,
                                             u16* __restrict__ feaT,
                                             float* __restrict__ pp,
                                             u16* __restrict__ Wpad) {
    __shared__ float4 sp[NPTS];          // 128 KB (aux roles reuse as scratch)
    __shared__ unsigned sWin[SPTS];      // 8 KB
    __shared__ u64 sAtom[4];
    __shared__ int slot0s;
    int bid = blockIdx.x;
    int tid = threadIdx.x;
    if (bid >= 4) {
        if (bid < 68) {
            // ---- transpose fea (B,C,N) f32 -> feaT (B,N,C) bf16; 4 tiles ----
            u16(*T)[130] = (u16(*)[130])sp;  // 33 KB within sp
            int base_t = (bid - 4) * 4;
#pragma unroll 1
            for (int k = 0; k < 4; ++k) {
                int tidx = base_t + k;
                int b = tidx >> 6, nt = tidx & 63;
                int n0 = nt * 128;
#pragma unroll 4
                for (int it = 0; it < 16; ++it) {
                    int idx = it * 1024 + tid;
                    int c = idx >> 7, nl = idx & 127;
                    T[nl][c] = f2b(fea[((size_t)(b * CH + c)) * NPTS + n0 + nl]);
                }
                __syncthreads();
#pragma unroll 4
                for (int it = 0; it < 16; ++it) {
                    int idx = it * 1024 + tid;
                    int nl = idx >> 7, c = idx & 127;
                    feaT[((size_t)(b * NPTS + n0 + nl)) * CH + c] = T[nl][c];
                }
                __syncthreads();
            }
        } else if (bid < 100) {
            // ---- pp = |p|^2 (np.sum LTR) ----
            int gid = (bid - 68) * 1024 + tid;
            int n = gid & 8191, b = gid >> 13;
            const float* cb = coor + b * 3 * NPTS;
            float x = cb[n], y = cb[NPTS + n], z = cb[2 * NPTS + n];
            pp[gid] = __fadd_rn(__fadd_rn(__fmul_rn(x, x), __fmul_rn(y, y)),
                                __fmul_rn(z, z));
        } else {
            // ---- W pad to bf16 ----
            int i = (bid - 100) * 1024 + tid;   // < 40960 = 256*160
            int d = i / CINP, k = i - d * CINP;
            Wpad[i] = (k < 131) ? f2b(W[d * 131 + k]) : (u16)0;
        }
        return;
    }
    // ================= FPS role (R11 verbatim) =================
    int b = bid;
    int lane = tid & 63;
    const float* gx = sxg + b * NPTS;
    const float* gy = syg + b * NPTS;
    const float* gz = szg + b * NPTS;
    const int* go = sog + b * NPTS;
    f32x2 X2[4], Y2[4], Z2[4], D2[4];
    unsigned PK[8];
    int n0 = tid * 8;
    if (tid < 4) sAtom[tid] = 0;
    float lox, hix, loy, hiy, loz, hiz;  // per-lane bbox of this lane's 8 pts
#pragma unroll
    for (int j = 0; j < 8; ++j) {
        float x = gx[n0 + j], y = gy[n0 + j], z = gz[n0 + j];
        sp[n0 + j] = make_float4(x, y, z, 0.0f);
        X2[j >> 1][j & 1] = x; Y2[j >> 1][j & 1] = y; Z2[j >> 1][j & 1] = z;
        D2[j >> 1][j & 1] = 1e10f;
        int oi = go[n0 + j];
        PK[j] = ((unsigned)oi << 16) | (unsigned)(n0 + j);
        if (oi == 0) slot0s = n0 + j;
        if (j == 0) {
            lox = hix = x; loy = hiy = y; loz = hiz = z;
        } else {
            lox = fminf(lox, x); hix = fmaxf(hix, x);
            loy = fminf(loy, y); hiy = fmaxf(hiy, y);
            loz = fminf(loz, z); hiz = fmaxf(hiz, z);
        }
    }
    __syncthreads();
    int far = slot0s;
    if (tid == 0) sWin[0] = (unsigned)slot0s;  // origIdx 0 in high bits
    float lm = 3.4e38f;     // lane max D (exact); forces update on first iter
    u64 cachedKey = 1;      // any real key beats it
    for (int t = 1; t < SPTS; ++t) {
        float4 c = sp[far];  // uniform addr -> broadcast ds_read_b128
        float fx = c.x, fy = c.y, fz = c.z;
        // exact per-lane skip: min dist(c, lane bbox)^2 vs lane max D
        float ddx = fmaxf(0.0f, fmaxf(lox - fx, fx - hix));
        float ddy = fmaxf(0.0f, fmaxf(loy - fy, fy - hiy));
        float ddz = fmaxf(0.0f, fmaxf(loz - fz, fz - hiz));
        float dmin2 = ddx * ddx + ddy * ddy + ddz * ddz;
        if (__ballot(dmin2 * 0.9995f < lm) != 0ull) {  // any lane might change
            {
#pragma clang fp contract(off)
                f32x2 fx2 = {fx, fx}, fy2 = {fy, fy}, fz2 = {fz, fz};
#pragma unroll
                for (int i = 0; i < 4; ++i) {
                    f32x2 dx = X2[i] - fx2;
                    f32x2 dy = Y2[i] - fy2;
                    f32x2 dz = Z2[i] - fz2;
                    f32x2 s = (dx * dx + dy * dy) + dz * dz;  // per-elem RN, np order
                    D2[i] = __builtin_elementwise_min(D2[i], s);
                }
            }
            // thread argmax: packed value tree, then min-PK among ties
            f32x2 t01 = __builtin_elementwise_max(D2[0], D2[1]);
            f32x2 t23 = __builtin_elementwise_max(D2[2], D2[3]);
            f32x2 t03 = __builtin_elementwise_max(t01, t23);
            float m = fmaxf(t03[0], t03[1]);
            lm = m;  // lane max D, exact
            unsigned sel = 0xFFFFFFFFu;
#pragma unroll
            for (int j = 0; j < 8; ++j) {
                float dj = D2[j >> 1][j & 1];
                sel = (dj == m) ? (sel < PK[j] ? sel : PK[j]) : sel;
            }
            // wave value-max via DPP on float bits (all >= 0)
            unsigned mbits = __float_as_uint(m);
            unsigned r = mbits;
            r = dpp_maxu<0xB1>(r);    // quad_perm xor1
            r = dpp_maxu<0x4E>(r);    // quad_perm xor2
            r = dpp_maxu<0x141>(r);   // row_half_mirror
            r = dpp_maxu<0x140>(r);   // row_mirror
            r = dpp_maxu<0x142>(r);   // row_bcast:15
            r = dpp_maxu<0x143>(r);   // row_bcast:31
            unsigned wmaxb = (unsigned)__builtin_amdgcn_readlane((int)r, 63);
            u64 ball = __ballot(mbits == wmaxb);
            unsigned wpk;
            if (__popcll(ball) == 1) {  // unique winner lane (common)
                int l = __ffsll(ball) - 1;
                wpk = (unsigned)__builtin_amdgcn_readlane((int)sel, l);
            } else {                    // rare: cross-lane value tie
                u64 kk = (mbits == wmaxb) ? (((u64)wmaxb << 32) | (unsigned)~sel) : 0ull;
                kk = dpp_max64<0xB1>(kk);
                kk = dpp_max64<0x4E>(kk);
                kk = dpp_max64<0x141>(kk);
                kk = dpp_max64<0x140>(kk);
                kk = dpp_max64<0x142>(kk);
                kk = dpp_max64<0x143>(kk);
                unsigned lo = (unsigned)__builtin_amdgcn_readlane((int)(unsigned)kk, 63);
                wpk = ~lo;
            }
            cachedKey = ((u64)wmaxb << 32) | (unsigned)~wpk;
        }
        if (lane == 63) atomicMax(&sAtom[t & 3], cachedKey);
        if (tid == 0) sAtom[(t + 1) & 3] = 0;  // slot quiescent this window
        __syncthreads();
        u64 wk = sAtom[t & 3];  // broadcast ds_read_b64
        unsigned pk = ~(unsigned)wk;
        far = (int)(pk & 0xFFFFu);
        if (tid == 0) sWin[t] = pk;
    }
    __syncthreads();
    // deferred flush
    for (int i = tid; i < SPTS; i += 1024) {
        unsigned pk = sWin[i];
        int slot = (int)(pk & 0xFFFFu);
        float4 c = sp[slot];
        fpsIdx[b * SPTS + i] = (int)(pk >> 16);
        float* oc = outCoor + b * 3 * SPTS + i;
        oc[0] = c.x; oc[SPTS] = c.y; oc[2 * SPTS] = c.z;
    }
}

// ---------------- grouping (exact f32, GEMM-style FMA dot): 1 wave/row ----------------
__global__ __launch_bounds__(256) void kgroup(const float* __restrict__ coor,
                                              const float* __restrict__ pp,
                                              const int* __restrict__ fpsIdx,
                                              int* __restrict__ gidxOut) {
    __shared__ u64 buf[4][256];
    __shared__ int cnt[4];
    int tid = threadIdx.x;
    int wv = tid >> 6, lane = tid & 63;
    if (tid < 4) cnt[tid] = 0;
    __syncthreads();
    int row = blockIdx.x * 4 + wv;
    int b = row >> 11, s = row & 2047;
    const float* cb = coor + b * 3 * NPTS;
    int n0 = fpsIdx[b * SPTS + s];
    float cx = cb[n0], cy = cb[NPTS + n0], cz = cb[2 * NPTS + n0];
    float cc = __fadd_rn(__fadd_rn(__fmul_rn(cx, cx), __fmul_rn(cy, cy)),
                         __fmul_rn(cz, cz));
    const float* ppb = pp + b * NPTS;
    u64 mk = ~0ull;
    for (int n = lane; n < NPTS; n += 64) {
        float x = cb[n], y = cb[NPTS + n], z = cb[2 * NPTS + n];
        float dot = __fmaf_rn(cz, z, __fmaf_rn(cy, y, __fmul_rn(cx, x)));
        float sq = __fsub_rn(__fadd_rn(cc, ppb[n]), __fmul_rn(2.0f, dot));
        unsigned ub = __float_as_uint(sq);
        ub ^= (ub >> 31) ? 0xFFFFFFFFu : 0x80000000u;
        u64 key = ((u64)ub << 32) | (unsigned)n;
        mk = umin64(mk, key);
        if (sq <= 0.01f) {
            int p = atomicAdd(&cnt[wv], 1);
            if (p < 256) buf[wv][p] = key;
        }
    }
#pragma unroll
    for (int off = 32; off > 0; off >>= 1) mk = umin64(mk, __shfl_xor(mk, off));
    int C = cnt[wv];
    if (C > 256) C = 256;
    int* go = gidxOut + row * KN;
    if (C <= 32) {
        if (lane < 32) {
            unsigned idx = (lane < C) ? (unsigned)buf[wv][lane] : (unsigned)mk;
            go[lane] = (int)idx;
        }
    } else {
        u64 e[4];
#pragma unroll
        for (int i = 0; i < 4; ++i) {
            int j2 = lane + (i << 6);
            e[i] = (j2 < C) ? buf[wv][j2] : ~0ull;
        }
        int cl = 0;
        unsigned sel = 0;
        for (int it = 0; it < 32; ++it) {
            u64 lb = ~0ull;
            int li = 0;
#pragma unroll
            for (int i = 0; i < 4; ++i) {
                bool f = (((cl >> i) & 1) == 0) && (e[i] < lb);
                lb = f ? e[i] : lb;
                li = f ? i : li;
            }
            u64 wmin = lb;
#pragma unroll
            for (int off = 32; off > 0; off >>= 1) wmin = umin64(wmin, __shfl_xor(wmin, off));
            u64 bal = __ballot(lb == wmin);
            int src = __ffsll((unsigned long long)bal) - 1;
            if (lane == src) cl |= (1 << li);
            if (lane == it) sel = (unsigned)wmin;
        }
        if (lane < 32) go[lane] = (int)sel;
    }
}

// ---------------- MLP + BN + ReLU + maxpool: 1 block per (b,s) row ----------------
__global__ __launch_bounds__(256) void kfeat(const float* __restrict__ coor,
                                             const u16* __restrict__ feaT,
                                             const u16* __restrict__ Wpad,
                                             const float* __restrict__ bias,
                                             const float* __restrict__ gamma,
                                             const float* __restrict__ beta,
                                             const float* __restrict__ bmean,
                                             const float* __restrict__ bvar,
                                             const int* __restrict__ fpsIdx,
                                             const int* __restrict__ gidx,
                                             float* __restrict__ outFea) {
    __shared__ u16 g[KN][168];
    int row = blockIdx.x;
    int b = row >> 11, s = row & 2047;
    int tid = threadIdx.x;
    {
        int k = tid >> 3, j = tid & 7;
        const float* cb = coor + b * 3 * NPTS;
        int nc = fpsIdx[b * SPTS + s];
        int nbr = gidx[row * KN + k];
        const uint4* f4 = (const uint4*)(feaT + (((size_t)b * NPTS + nbr) << 7));
        uint4* gr = (uint4*)&g[k][0];
        gr[j] = f4[j];
        gr[j + 8] = f4[j + 8];
        for (int c = 128 + j; c < CINP; c += 8) {
            u16 v = 0;
            if (c < 131) {
                int dim = c - 128;
                float pv = cb[dim * NPTS + nbr];
                float cv = cb[dim * NPTS + nc];
                v = f2b(__fdiv_rn(__fsub_rn(pv, cv), 0.1f));
            }
            g[k][c] = v;
        }
    }
    __syncthreads();
    int w = tid >> 6, lane = tid & 63;
    int mrow = lane & 15, q = lane >> 4;
    f32x4 acc[4][2] = {};
#pragma unroll
    for (int ks = 0; ks < 5; ++ks) {
        int kb = ks * 32 + q * 8;
        bf16x8 b0 = *(const bf16x8*)&g[mrow][kb];
        bf16x8 b1 = *(const bf16x8*)&g[mrow + 16][kb];
#pragma unroll
        for (int mt = 0; mt < 4; ++mt) {
            bf16x8 a = *(const bf16x8*)&Wpad[(size_t)(w * 64 + mt * 16 + mrow) * CINP + kb];
            acc[mt][0] = __builtin_amdgcn_mfma_f32_16x16x32_bf16(a, b0, acc[mt][0], 0, 0, 0);
            acc[mt][1] = __builtin_amdgcn_mfma_f32_16x16x32_bf16(a, b1, acc[mt][1], 0, 0, 0);
        }
    }
#pragma unroll
    for (int mt = 0; mt < 4; ++mt) {
#pragma unroll
        for (int r = 0; r < 4; ++r) {
            int m = w * 64 + mt * 16 + q * 4 + r;
            float ga = gamma[m], be = beta[m];
            float mu = bmean[m], va = bvar[m], bi = bias[m];
            float rs = 1.0f / sqrtf(va + 1e-5f);
            float h0 = acc[mt][0][r] + bi;
            h0 = fmaxf(ga * (h0 - mu) * rs + be, 0.0f);
            float h1 = acc[mt][1][r] + bi;
            h1 = fmaxf(ga * (h1 - mu) * rs + be, 0.0f);
            float v = fmaxf(h0, h1);
#pragma unroll
            for (int off = 1; off < 16; off <<= 1) v = fmaxf(v, __shfl_xor(v, off));
            if (mrow == 0) outFea[((size_t)(b * 256 + m)) * SPTS + s] = v;
        }
    }
}

extern "C" void kernel_launch(void* const* d_in, const int* in_sizes, int n_in,
                              void* d_out, int out_size, void* d_ws, size_t ws_size,
                              hipStream_t stream) {
    const float* coor = (const float*)d_in[0];
    const float* fea = (const float*)d_in[1];
    const float* W = (const float*)d_in[2];
    const float* bias = (const float*)d_in[3];
    const float* gamma = (const float*)d_in[4];
    const float* beta = (const float*)d_in[5];
    const float* bmean = (const float*)d_in[6];
    const float* bvar = (const float*)d_in[7];
    char* ws = (char*)d_ws;
    int* fpsIdx = (int*)ws;                              // 32 KB
    int* gidx = (int*)(ws + 32768);                      // 1 MB
    float* pp = (float*)(ws + 32768 + 1048576);          // 128 KB
    u16* feaT = (u16*)(ws + 1212416);                    // 8 MB bf16
    u16* Wpad = (u16*)(ws + 9601024);                    // 80 KB bf16
    float* sxg = (float*)(ws + 9682944);                 // 128 KB
    float* syg = (float*)(ws + 9814016);                 // 128 KB
    float* szg = (float*)(ws + 9945088);                 // 128 KB
    int* sog = (int*)(ws + 10076160);                    // 128 KB
    float* outC = (float*)d_out;                         // (B,3,S) f32
    float* outF = outC + NB * 3 * SPTS;                  // (B,2C,S) f32

    ksort<<<NB, 256, 0, stream>>>(coor, sxg, syg, szg, sog);
    kfps<<<140, 1024, 0, stream>>>(sxg, syg, szg, sog, fpsIdx, outC,
                                   fea, coor, W, feaT, pp, Wpad);
    kgroup<<<2048, 256, 0, stream>>>(coor, pp, fpsIdx, gidx);
    kfeat<<<8192, 256, 0, stream>>>(coor, feaT, Wpad, bias, gamma, beta, bmean, bvar,
                                    fpsIdx, gidx, outF);
}

// Round 7
// 1528.240 us; speedup vs baseline: 1.1893x; 1.0886x over previous
//
#include <hip/hip_runtime.h>
#include <stdint.h>

// SetAbstraction (PointNet++): B=4, N=8192, C=128, S=2048, K=32, R=0.1
// Numerics locked (R5 passed, absmax 0.0156):
//  - FPS: f32, d = ((dx*dx + dy*dy) + dz*dz) mul/add LTR (np.sum order)
//  - grouping: sq = (cc+pp) - 2*dot, dot = fma(cz,z, fma(cy,y, cx*x)) (BLAS)
//  - MLP: bf16 MFMA
// R15: Morton-order ksort (8x8x8 = 512 bins, bit-interleaved). Wave-level
// skip requires ALL 64 lanes to pass; critical path = slowest wave. Old
// xy-major order made each wave span the full z-column (update prob ~0.17);
// Morton blocks are 3D-compact (~0.25x0.25x0.125) -> wave update prob ~0.05,
// expected updating waves/iter ~3.6 -> ~1.8. Sort permutation is semantics-
// free (PK carries original index; argmax tie-break = min origIdx, matching
// jnp.argmax). FPS loop and mega-dispatch structure unchanged from R14.

typedef unsigned short u16;
typedef unsigned long long u64;
typedef __bf16 bf16x8 __attribute__((ext_vector_type(8)));
typedef float f32x4 __attribute__((ext_vector_type(4)));
typedef float f32x2 __attribute__((ext_vector_type(2)));

#define NB 4
#define NPTS 8192
#define CH 128
#define SPTS 2048
#define KN 32
#define CINP 160   // 131 padded to 160 (5 k-steps of 32)

__device__ __forceinline__ u16 f2b(float f) {  // f32 -> bf16 RNE
    unsigned x = __float_as_uint(f);
    unsigned r = (x + 0x7fffu + ((x >> 16) & 1u)) >> 16;
    return (u16)r;
}
__device__ __forceinline__ u64 umin64(u64 a, u64 b) { return a < b ? a : b; }
// spread 3-bit value to bit positions 0,3,6
__device__ __forceinline__ int mort3(int v) {
    return (v & 1) | ((v & 2) << 2) | ((v & 4) << 4);
}

template <int CTRL>
__device__ __forceinline__ u64 dpp_max64(u64 k) {
    unsigned lo = (unsigned)k, hi = (unsigned)(k >> 32);
    unsigned mlo = (unsigned)__builtin_amdgcn_update_dpp((int)lo, (int)lo, CTRL, 0xF, 0xF, false);
    unsigned mhi = (unsigned)__builtin_amdgcn_update_dpp((int)hi, (int)hi, CTRL, 0xF, 0xF, false);
    u64 m = ((u64)mhi << 32) | mlo;
    return m > k ? m : k;
}
// uint-bits max (== float max for non-negative floats)
template <int CTRL>
__device__ __forceinline__ unsigned dpp_maxu(unsigned v) {
    unsigned mv = (unsigned)__builtin_amdgcn_update_dpp((int)v, (int)v, CTRL, 0xF, 0xF, false);
    return mv > v ? mv : v;
}

// ------- spatial counting sort into 512 Morton bins (8x8x8) -------
__global__ __launch_bounds__(256) void ksort(const float* __restrict__ coor,
                                             float* __restrict__ sxg,
                                             float* __restrict__ syg,
                                             float* __restrict__ szg,
                                             int* __restrict__ sog) {
    __shared__ int hist[512], base[512];
    int b = blockIdx.x, tid = threadIdx.x;
    const float* cb = coor + b * 3 * NPTS;
    hist[tid] = 0;
    hist[tid + 256] = 0;
    __syncthreads();
    int bins[32];
#pragma unroll 4
    for (int i = 0; i < 32; ++i) {
        int n = tid * 32 + i;
        float x = cb[n], y = cb[NPTS + n], z = cb[2 * NPTS + n];
        int bx = min(7, (int)(x * 8.0f));
        int by = min(7, (int)(y * 8.0f));
        int bz = min(7, (int)(z * 8.0f));
        int bin = mort3(bx) | (mort3(by) << 1) | (mort3(bz) << 2);
        bins[i] = bin;
        atomicAdd(&hist[bin], 1);
    }
    __syncthreads();
    if (tid == 0) {
        int acc = 0;
        for (int k2 = 0; k2 < 512; ++k2) { base[k2] = acc; acc += hist[k2]; hist[k2] = 0; }
    }
    __syncthreads();
#pragma unroll 4
    for (int i = 0; i < 32; ++i) {
        int n = tid * 32 + i;
        int bin = bins[i];
        int pos = base[bin] + atomicAdd(&hist[bin], 1);
        sxg[b * NPTS + pos] = cb[n];
        syg[b * NPTS + pos] = cb[NPTS + n];
        szg[b * NPTS + pos] = cb[2 * NPTS + n];
        sog[b * NPTS + pos] = n;
    }
}

// ---- FPS mega-dispatch: blocks 0-3 FPS (R11 verbatim); 4-67 ktrans;
// ---- 68-99 pp; 100-139 Wpad. Aux blocks run on idle CUs concurrently.
__global__ __launch_bounds__(1024) void kfps(const float* __restrict__ sxg,
                                             const float* __restrict__ syg,
                                             const float* __restrict__ szg,
                                             const int* __restrict__ sog,
                                             int* __restrict__ fpsIdx,
                                             float* __restrict__ outCoor,
                                             const float* __restrict__ fea,
                                             const float* __restrict__ coor,
                                             const float* __restrict__ W,
                                             u16* __restrict__ feaT,
                                             float* __restrict__ pp,
                                             u16* __restrict__ Wpad) {
    __shared__ float4 sp[NPTS];          // 128 KB (aux roles reuse as scratch)
    __shared__ unsigned sWin[SPTS];      // 8 KB
    __shared__ u64 sAtom[4];
    __shared__ int slot0s;
    int bid = blockIdx.x;
    int tid = threadIdx.x;
    if (bid >= 4) {
        if (bid < 68) {
            // ---- transpose fea (B,C,N) f32 -> feaT (B,N,C) bf16; 4 tiles ----
            u16(*T)[130] = (u16(*)[130])sp;  // 33 KB within sp
            int base_t = (bid - 4) * 4;
#pragma unroll 1
            for (int k = 0; k < 4; ++k) {
                int tidx = base_t + k;
                int b = tidx >> 6, nt = tidx & 63;
                int n0 = nt * 128;
#pragma unroll 4
                for (int it = 0; it < 16; ++it) {
                    int idx = it * 1024 + tid;
                    int c = idx >> 7, nl = idx & 127;
                    T[nl][c] = f2b(fea[((size_t)(b * CH + c)) * NPTS + n0 + nl]);
                }
                __syncthreads();
#pragma unroll 4
                for (int it = 0; it < 16; ++it) {
                    int idx = it * 1024 + tid;
                    int nl = idx >> 7, c = idx & 127;
                    feaT[((size_t)(b * NPTS + n0 + nl)) * CH + c] = T[nl][c];
                }
                __syncthreads();
            }
        } else if (bid < 100) {
            // ---- pp = |p|^2 (np.sum LTR) ----
            int gid = (bid - 68) * 1024 + tid;
            int n = gid & 8191, b = gid >> 13;
            const float* cb = coor + b * 3 * NPTS;
            float x = cb[n], y = cb[NPTS + n], z = cb[2 * NPTS + n];
            pp[gid] = __fadd_rn(__fadd_rn(__fmul_rn(x, x), __fmul_rn(y, y)),
                                __fmul_rn(z, z));
        } else {
            // ---- W pad to bf16 ----
            int i = (bid - 100) * 1024 + tid;   // < 40960 = 256*160
            int d = i / CINP, k = i - d * CINP;
            Wpad[i] = (k < 131) ? f2b(W[d * 131 + k]) : (u16)0;
        }
        return;
    }
    // ================= FPS role (R11 verbatim) =================
    int b = bid;
    int lane = tid & 63;
    const float* gx = sxg + b * NPTS;
    const float* gy = syg + b * NPTS;
    const float* gz = szg + b * NPTS;
    const int* go = sog + b * NPTS;
    f32x2 X2[4], Y2[4], Z2[4], D2[4];
    unsigned PK[8];
    int n0 = tid * 8;
    if (tid < 4) sAtom[tid] = 0;
    float lox, hix, loy, hiy, loz, hiz;  // per-lane bbox of this lane's 8 pts
#pragma unroll
    for (int j = 0; j < 8; ++j) {
        float x = gx[n0 + j], y = gy[n0 + j], z = gz[n0 + j];
        sp[n0 + j] = make_float4(x, y, z, 0.0f);
        X2[j >> 1][j & 1] = x; Y2[j >> 1][j & 1] = y; Z2[j >> 1][j & 1] = z;
        D2[j >> 1][j & 1] = 1e10f;
        int oi = go[n0 + j];
        PK[j] = ((unsigned)oi << 16) | (unsigned)(n0 + j);
        if (oi == 0) slot0s = n0 + j;
        if (j == 0) {
            lox = hix = x; loy = hiy = y; loz = hiz = z;
        } else {
            lox = fminf(lox, x); hix = fmaxf(hix, x);
            loy = fminf(loy, y); hiy = fmaxf(hiy, y);
            loz = fminf(loz, z); hiz = fmaxf(hiz, z);
        }
    }
    __syncthreads();
    int far = slot0s;
    if (tid == 0) sWin[0] = (unsigned)slot0s;  // origIdx 0 in high bits
    float lm = 3.4e38f;     // lane max D (exact); forces update on first iter
    u64 cachedKey = 1;      // any real key beats it
    for (int t = 1; t < SPTS; ++t) {
        float4 c = sp[far];  // uniform addr -> broadcast ds_read_b128
        float fx = c.x, fy = c.y, fz = c.z;
        // exact per-lane skip: min dist(c, lane bbox)^2 vs lane max D
        float ddx = fmaxf(0.0f, fmaxf(lox - fx, fx - hix));
        float ddy = fmaxf(0.0f, fmaxf(loy - fy, fy - hiy));
        float ddz = fmaxf(0.0f, fmaxf(loz - fz, fz - hiz));
        float dmin2 = ddx * ddx + ddy * ddy + ddz * ddz;
        if (__ballot(dmin2 * 0.9995f < lm) != 0ull) {  // any lane might change
            {
#pragma clang fp contract(off)
                f32x2 fx2 = {fx, fx}, fy2 = {fy, fy}, fz2 = {fz, fz};
#pragma unroll
                for (int i = 0; i < 4; ++i) {
                    f32x2 dx = X2[i] - fx2;
                    f32x2 dy = Y2[i] - fy2;
                    f32x2 dz = Z2[i] - fz2;
                    f32x2 s = (dx * dx + dy * dy) + dz * dz;  // per-elem RN, np order
                    D2[i] = __builtin_elementwise_min(D2[i], s);
                }
            }
            // thread argmax: packed value tree, then min-PK among ties
            f32x2 t01 = __builtin_elementwise_max(D2[0], D2[1]);
            f32x2 t23 = __builtin_elementwise_max(D2[2], D2[3]);
            f32x2 t03 = __builtin_elementwise_max(t01, t23);
            float m = fmaxf(t03[0], t03[1]);
            lm = m;  // lane max D, exact
            unsigned sel = 0xFFFFFFFFu;
#pragma unroll
            for (int j = 0; j < 8; ++j) {
                float dj = D2[j >> 1][j & 1];
                sel = (dj == m) ? (sel < PK[j] ? sel : PK[j]) : sel;
            }
            // wave value-max via DPP on float bits (all >= 0)
            unsigned mbits = __float_as_uint(m);
            unsigned r = mbits;
            r = dpp_maxu<0xB1>(r);    // quad_perm xor1
            r = dpp_maxu<0x4E>(r);    // quad_perm xor2
            r = dpp_maxu<0x141>(r);   // row_half_mirror
            r = dpp_maxu<0x140>(r);   // row_mirror
            r = dpp_maxu<0x142>(r);   // row_bcast:15
            r = dpp_maxu<0x143>(r);   // row_bcast:31
            unsigned wmaxb = (unsigned)__builtin_amdgcn_readlane((int)r, 63);
            u64 ball = __ballot(mbits == wmaxb);
            unsigned wpk;
            if (__popcll(ball) == 1) {  // unique winner lane (common)
                int l = __ffsll(ball) - 1;
                wpk = (unsigned)__builtin_amdgcn_readlane((int)sel, l);
            } else {                    // rare: cross-lane value tie
                u64 kk = (mbits == wmaxb) ? (((u64)wmaxb << 32) | (unsigned)~sel) : 0ull;
                kk = dpp_max64<0xB1>(kk);
                kk = dpp_max64<0x4E>(kk);
                kk = dpp_max64<0x141>(kk);
                kk = dpp_max64<0x140>(kk);
                kk = dpp_max64<0x142>(kk);
                kk = dpp_max64<0x143>(kk);
                unsigned lo = (unsigned)__builtin_amdgcn_readlane((int)(unsigned)kk, 63);
                wpk = ~lo;
            }
            cachedKey = ((u64)wmaxb << 32) | (unsigned)~wpk;
        }
        if (lane == 63) atomicMax(&sAtom[t & 3], cachedKey);
        if (tid == 0) sAtom[(t + 1) & 3] = 0;  // slot quiescent this window
        __syncthreads();
        u64 wk = sAtom[t & 3];  // broadcast ds_read_b64
        unsigned pk = ~(unsigned)wk;
        far = (int)(pk & 0xFFFFu);
        if (tid == 0) sWin[t] = pk;
    }
    __syncthreads();
    // deferred flush
    for (int i = tid; i < SPTS; i += 1024) {
        unsigned pk = sWin[i];
        int slot = (int)(pk & 0xFFFFu);
        float4 c = sp[slot];
        fpsIdx[b * SPTS + i] = (int)(pk >> 16);
        float* oc = outCoor + b * 3 * SPTS + i;
        oc[0] = c.x; oc[SPTS] = c.y; oc[2 * SPTS] = c.z;
    }
}

// ---------------- grouping (exact f32, GEMM-style FMA dot): 1 wave/row ----------------
__global__ __launch_bounds__(256) void kgroup(const float* __restrict__ coor,
                                              const float* __restrict__ pp,
                                              const int* __restrict__ fpsIdx,
                                              int* __restrict__ gidxOut) {
    __shared__ u64 buf[4][256];
    __shared__ int cnt[4];
    int tid = threadIdx.x;
    int wv = tid >> 6, lane = tid & 63;
    if (tid < 4) cnt[tid] = 0;
    __syncthreads();
    int row = blockIdx.x * 4 + wv;
    int b = row >> 11, s = row & 2047;
    const float* cb = coor + b * 3 * NPTS;
    int n0 = fpsIdx[b * SPTS + s];
    float cx = cb[n0], cy = cb[NPTS + n0], cz = cb[2 * NPTS + n0];
    float cc = __fadd_rn(__fadd_rn(__fmul_rn(cx, cx), __fmul_rn(cy, cy)),
                         __fmul_rn(cz, cz));
    const float* ppb = pp + b * NPTS;
    u64 mk = ~0ull;
    for (int n = lane; n < NPTS; n += 64) {
        float x = cb[n], y = cb[NPTS + n], z = cb[2 * NPTS + n];
        float dot = __fmaf_rn(cz, z, __fmaf_rn(cy, y, __fmul_rn(cx, x)));
        float sq = __fsub_rn(__fadd_rn(cc, ppb[n]), __fmul_rn(2.0f, dot));
        unsigned ub = __float_as_uint(sq);
        ub ^= (ub >> 31) ? 0xFFFFFFFFu : 0x80000000u;
        u64 key = ((u64)ub << 32) | (unsigned)n;
        mk = umin64(mk, key);
        if (sq <= 0.01f) {
            int p = atomicAdd(&cnt[wv], 1);
            if (p < 256) buf[wv][p] = key;
        }
    }
#pragma unroll
    for (int off = 32; off > 0; off >>= 1) mk = umin64(mk, __shfl_xor(mk, off));
    int C = cnt[wv];
    if (C > 256) C = 256;
    int* go = gidxOut + row * KN;
    if (C <= 32) {
        if (lane < 32) {
            unsigned idx = (lane < C) ? (unsigned)buf[wv][lane] : (unsigned)mk;
            go[lane] = (int)idx;
        }
    } else {
        u64 e[4];
#pragma unroll
        for (int i = 0; i < 4; ++i) {
            int j2 = lane + (i << 6);
            e[i] = (j2 < C) ? buf[wv][j2] : ~0ull;
        }
        int cl = 0;
        unsigned sel = 0;
        for (int it = 0; it < 32; ++it) {
            u64 lb = ~0ull;
            int li = 0;
#pragma unroll
            for (int i = 0; i < 4; ++i) {
                bool f = (((cl >> i) & 1) == 0) && (e[i] < lb);
                lb = f ? e[i] : lb;
                li = f ? i : li;
            }
            u64 wmin = lb;
#pragma unroll
            for (int off = 32; off > 0; off >>= 1) wmin = umin64(wmin, __shfl_xor(wmin, off));
            u64 bal = __ballot(lb == wmin);
            int src = __ffsll((unsigned long long)bal) - 1;
            if (lane == src) cl |= (1 << li);
            if (lane == it) sel = (unsigned)wmin;
        }
        if (lane < 32) go[lane] = (int)sel;
    }
}

// ---------------- MLP + BN + ReLU + maxpool: 1 block per (b,s) row ----------------
__global__ __launch_bounds__(256) void kfeat(const float* __restrict__ coor,
                                             const u16* __restrict__ feaT,
                                             const u16* __restrict__ Wpad,
                                             const float* __restrict__ bias,
                                             const float* __restrict__ gamma,
                                             const float* __restrict__ beta,
                                             const float* __restrict__ bmean,
                                             const float* __restrict__ bvar,
                                             const int* __restrict__ fpsIdx,
                                             const int* __restrict__ gidx,
                                             float* __restrict__ outFea) {
    __shared__ u16 g[KN][168];
    int row = blockIdx.x;
    int b = row >> 11, s = row & 2047;
    int tid = threadIdx.x;
    {
        int k = tid >> 3, j = tid & 7;
        const float* cb = coor + b * 3 * NPTS;
        int nc = fpsIdx[b * SPTS + s];
        int nbr = gidx[row * KN + k];
        const uint4* f4 = (const uint4*)(feaT + (((size_t)b * NPTS + nbr) << 7));
        uint4* gr = (uint4*)&g[k][0];
        gr[j] = f4[j];
        gr[j + 8] = f4[j + 8];
        for (int c = 128 + j; c < CINP; c += 8) {
            u16 v = 0;
            if (c < 131) {
                int dim = c - 128;
                float pv = cb[dim * NPTS + nbr];
                float cv = cb[dim * NPTS + nc];
                v = f2b(__fdiv_rn(__fsub_rn(pv, cv), 0.1f));
            }
            g[k][c] = v;
        }
    }
    __syncthreads();
    int w = tid >> 6, lane = tid & 63;
    int mrow = lane & 15, q = lane >> 4;
    f32x4 acc[4][2] = {};
#pragma unroll
    for (int ks = 0; ks < 5; ++ks) {
        int kb = ks * 32 + q * 8;
        bf16x8 b0 = *(const bf16x8*)&g[mrow][kb];
        bf16x8 b1 = *(const bf16x8*)&g[mrow + 16][kb];
#pragma unroll
        for (int mt = 0; mt < 4; ++mt) {
            bf16x8 a = *(const bf16x8*)&Wpad[(size_t)(w * 64 + mt * 16 + mrow) * CINP + kb];
            acc[mt][0] = __builtin_amdgcn_mfma_f32_16x16x32_bf16(a, b0, acc[mt][0], 0, 0, 0);
            acc[mt][1] = __builtin_amdgcn_mfma_f32_16x16x32_bf16(a, b1, acc[mt][1], 0, 0, 0);
        }
    }
#pragma unroll
    for (int mt = 0; mt < 4; ++mt) {
#pragma unroll
        for (int r = 0; r < 4; ++r) {
            int m = w * 64 + mt * 16 + q * 4 + r;
            float ga = gamma[m], be = beta[m];
            float mu = bmean[m], va = bvar[m], bi = bias[m];
            float rs = 1.0f / sqrtf(va + 1e-5f);
            float h0 = acc[mt][0][r] + bi;
            h0 = fmaxf(ga * (h0 - mu) * rs + be, 0.0f);
            float h1 = acc[mt][1][r] + bi;
            h1 = fmaxf(ga * (h1 - mu) * rs + be, 0.0f);
            float v = fmaxf(h0, h1);
#pragma unroll
            for (int off = 1; off < 16; off <<= 1) v = fmaxf(v, __shfl_xor(v, off));
            if (mrow == 0) outFea[((size_t)(b * 256 + m)) * SPTS + s] = v;
        }
    }
}

extern "C" void kernel_launch(void* const* d_in, const int* in_sizes, int n_in,
                              void* d_out, int out_size, void* d_ws, size_t ws_size,
                              hipStream_t stream) {
    const float* coor = (const float*)d_in[0];
    const float* fea = (const float*)d_in[1];
    const float* W = (const float*)d_in[2];
    const float* bias = (const float*)d_in[3];
    const float* gamma = (const float*)d_in[4];
    const float* beta = (const float*)d_in[5];
    const float* bmean = (const float*)d_in[6];
    const float* bvar = (const float*)d_in[7];
    char* ws = (char*)d_ws;
    int* fpsIdx = (int*)ws;                              // 32 KB
    int* gidx = (int*)(ws + 32768);                      // 1 MB
    float* pp = (float*)(ws + 32768 + 1048576);          // 128 KB
    u16* feaT = (u16*)(ws + 1212416);                    // 8 MB bf16
    u16* Wpad = (u16*)(ws + 9601024);                    // 80 KB bf16
    float* sxg = (float*)(ws + 9682944);                 // 128 KB
    float* syg = (float*)(ws + 9814016);                 // 128 KB
    float* szg = (float*)(ws + 9945088);                 // 128 KB
    int* sog = (int*)(ws + 10076160);                    // 128 KB
    float* outC = (float*)d_out;                         // (B,3,S) f32
    float* outF = outC + NB * 3 * SPTS;                  // (B,2C,S) f32

    ksort<<<NB, 256, 0, stream>>>(coor, sxg, syg, szg, sog);
    kfps<<<140, 1024, 0, stream>>>(sxg, syg, szg, sog, fpsIdx, outC,
                                   fea, coor, W, feaT, pp, Wpad);
    kgroup<<<2048, 256, 0, stream>>>(coor, pp, fpsIdx, gidx);
    kfeat<<<8192, 256, 0, stream>>>(coor, feaT, Wpad, bias, gamma, beta, bmean, bvar,
                                    fpsIdx, gidx, outF);
}